// Round 11
// baseline (1182.632 us; speedup 1.0000x reference)
//
#include <hip/hip_runtime.h>
#include <hip/hip_bf16.h>

#define NN 50000
#define EE 800000
#define DD 300
#define GG 256
#define RS  320            // padded activation row stride (shorts)
#define RSU 80             // row stride in uint2

// GEMM geometry
#define NK1 10             // GEMM1 k-steps (K=320)
#define NT1 40             // GEMM1 col tiles (N=640)
#define NK2 19             // GEMM2 k-steps (K=608)
#define NT2 24             // GEMM2 col tiles (N=384)
#define PACK1 ((size_t)NT1 * NK1 * 512)   // shorts per layer
#define PACK2 ((size_t)NT2 * NK2 * 512)
#define HSTR 1216          // Hs row stride bytes (608 bf16)

#define SCB 49             // scan blocks (49 * 1024 >= NN)

typedef short bf16x8 __attribute__((ext_vector_type(8)));
typedef float f32x4  __attribute__((ext_vector_type(4)));

// float -> bf16 bits, round-to-nearest-even (finite inputs)
__device__ inline unsigned short f2bf(float f) {
    unsigned u = __float_as_uint(f);
    return (unsigned short)((u + 0x7fffu + ((u >> 16) & 1u)) >> 16);
}
__device__ inline unsigned pk2(float a, float b) {
    return (unsigned)f2bf(a) | ((unsigned)f2bf(b) << 16);
}
// a[0..7] += 8 bf16 unpacked from uint4
__device__ inline void acc8(float* a, uint4 v) {
    a[0] += __uint_as_float(v.x << 16); a[1] += __uint_as_float(v.x & 0xffff0000u);
    a[2] += __uint_as_float(v.y << 16); a[3] += __uint_as_float(v.y & 0xffff0000u);
    a[4] += __uint_as_float(v.z << 16); a[5] += __uint_as_float(v.z & 0xffff0000u);
    a[6] += __uint_as_float(v.w << 16); a[7] += __uint_as_float(v.w & 0xffff0000u);
}
__device__ inline int deg3(int p) {
    return (p & 1023) + ((p >> 10) & 1023) + ((p >> 20) & 1023);
}

// ===========================================================================
// CSR build (once per launch). deg derived from cnt1p (3x10-bit counts).
// ===========================================================================
__global__ __launch_bounds__(256)
void count_kernel(const int* __restrict__ ei, const int* __restrict__ ea,
                  int* __restrict__ cnt1p, int* __restrict__ cnt2p)
{
    int e = blockIdx.x * 256 + threadIdx.x;
    if (e >= EE) return;
    int dst = ei[EE + e];
    int a0  = ea[e * 2];
    int a1  = ea[e * 2 + 1];
    atomicAdd(&cnt1p[dst], 1 << (10 * a0));
    atomicAdd(&cnt2p[dst], 1 << (10 * a1));
}

// Hierarchical scan, phase 1: per-block degree sums (49 blocks x 1024 nodes)
__global__ __launch_bounds__(256)
void scan1_kernel(const int* __restrict__ cnt1p, int* __restrict__ blocksum)
{
    __shared__ int ws[4];
    int tid = threadIdx.x;
    int n0 = blockIdx.x * 1024 + tid * 4;
    int s = 0;
#pragma unroll
    for (int i = 0; i < 4; ++i) {
        int n = n0 + i;
        if (n < NN) s += deg3(cnt1p[n]);
    }
    for (int off = 1; off < 64; off <<= 1) s += __shfl_xor(s, off);
    if ((tid & 63) == 0) ws[tid >> 6] = s;
    __syncthreads();
    if (tid == 0) blocksum[blockIdx.x] = ws[0] + ws[1] + ws[2] + ws[3];
}

// Hierarchical scan, phase 2: block offset via predicated 64-lane reduce over
// the 49 block sums, intra-block shfl_up scan, write rowptr+cursor.
__global__ __launch_bounds__(256)
void scan2_kernel(const int* __restrict__ cnt1p, const int* __restrict__ blocksum,
                  int* __restrict__ rowptr, int* __restrict__ cursor)
{
    __shared__ int ws[4];
    __shared__ int boff;
    int tid = threadIdx.x;
    int b   = blockIdx.x;
    if (tid < 64) {
        int v = (tid < b) ? blocksum[tid] : 0;     // b <= 48 < 64
        for (int off = 1; off < 64; off <<= 1) v += __shfl_xor(v, off);
        if (tid == 0) boff = v;
    }
    int n0 = b * 1024 + tid * 4;
    int d[4]; int s = 0;
#pragma unroll
    for (int i = 0; i < 4; ++i) {
        int n = n0 + i;
        d[i] = (n < NN) ? deg3(cnt1p[n]) : 0;
        s += d[i];
    }
    int lane = tid & 63, w = tid >> 6;
    int inc = s;
    for (int off = 1; off < 64; off <<= 1) {
        int t = __shfl_up(inc, off);
        if (lane >= off) inc += t;
    }
    if (lane == 63) ws[w] = inc;
    __syncthreads();
    int woff = 0;
#pragma unroll
    for (int i = 0; i < 4; ++i) if (i < w) woff += ws[i];
    int excl = boff + woff + inc - s;
#pragma unroll
    for (int i = 0; i < 4; ++i) {
        int n = n0 + i;
        if (n < NN) { rowptr[n] = excl; cursor[n] = excl; }
        excl += d[i];
    }
    if (b == SCB - 1 && tid == 255) rowptr[NN] = EE;
}

__global__ __launch_bounds__(256)
void fill_kernel(const int* __restrict__ ei, int* __restrict__ cursor,
                 int* __restrict__ csr_src)
{
    int e = blockIdx.x * 256 + threadIdx.x;
    if (e >= EE) return;
    int dst = ei[EE + e];
    int src = ei[e];
    int pos = atomicAdd(&cursor[dst], 1);
    csr_src[pos] = src;
}

// ===========================================================================
// Pack ALL layers' W1+W2 -> bf16 MFMA B-fragments, kt-major:
// tile (nt_i,kt) at pos = kt*NT + nt_i. Lane l holds
// B[kt*32 + (l>>4)*8 + j][nt_i*16 + (l&15)], zero-padded outside K x N.
// ===========================================================================
__global__ __launch_bounds__(256)
void pack_all(const float* __restrict__ W1, const float* __restrict__ W2,
              short* __restrict__ W1p, short* __restrict__ W2p)
{
    const int TL = NT1 * NK1 + NT2 * NK2;   // 856 tiles/layer
    int idx = blockIdx.x * 256 + threadIdx.x;
    if (idx >= 5 * TL * 64) return;
    int lane  = idx & 63;
    int tile  = idx >> 6;
    int layer = tile / TL;
    int tl    = tile - layer * TL;
    const float* W; short* outp;
    int K, N, nt_i, kt, pos;
    if (tl < NT1 * NK1) {
        nt_i = tl / NK1; kt = tl % NK1;
        W = W1 + (size_t)layer * DD * 600;
        outp = W1p + layer * PACK1;
        K = 300; N = 600;
        pos = kt * NT1 + nt_i;
    } else {
        tl -= NT1 * NK1;
        nt_i = tl / NK2; kt = tl % NK2;
        W = W2 + (size_t)layer * 600 * DD;
        outp = W2p + layer * PACK2;
        K = 600; N = 300;
        pos = kt * NT2 + nt_i;
    }
    int col = nt_i * 16 + (lane & 15);
    int k0  = kt * 32 + (lane >> 4) * 8;
    unsigned short v[8];
#pragma unroll
    for (int j = 0; j < 8; ++j) {
        int r = k0 + j;
        float f = (r < K && col < N) ? W[(size_t)r * N + col] : 0.0f;
        v[j] = f2bf(f);
    }
    uint4 p;
    p.x = (unsigned)v[0] | ((unsigned)v[1] << 16);
    p.y = (unsigned)v[2] | ((unsigned)v[3] << 16);
    p.z = (unsigned)v[4] | ((unsigned)v[5] << 16);
    p.w = (unsigned)v[6] | ((unsigned)v[7] << 16);
    ((uint4*)outp)[(size_t)pos * 64 + lane] = p;
}

// ===========================================================================
// init: x (fp32 [N][300]) -> Xbf bf16 [N][320] zero-padded; zero Ybf pad cols.
// ===========================================================================
__global__ __launch_bounds__(256)
void init_kernel(const float* __restrict__ x, short* __restrict__ Xbf,
                 short* __restrict__ Ybf)
{
    int i = blockIdx.x * 256 + threadIdx.x;
    const int TX = NN * RSU;
    if (i < TX) {
        int row = i / RSU, pu = i - row * RSU;
        uint2 o = make_uint2(0u, 0u);
        if (pu < 75) {
            float4 v = ((const float4*)x)[row * 75 + pu];
            o = make_uint2(pk2(v.x, v.y), pk2(v.z, v.w));
        }
        ((uint2*)Xbf)[i] = o;
    } else {
        int j = i - TX;
        if (j < (NN + 64) * 5) {
            int row = j / 5, pu = 75 + (j - row * 5);
            ((uint2*)Ybf)[(size_t)row * RSU + pu] = make_uint2(0u, 0u);
        }
    }
}

// ===========================================================================
// Aggregation: one wave per node, 40 active lanes, uint4 (16B) row chunks,
// depth-4 pipeline + INDEX PREFETCH (R10-proven, ~100us): next iteration's 4
// csr_src indices loaded while current rows are consumed.
// agg[n] = h[n] + ee-self + sum_t cnt*ee[t] + sum_in h[src]
// ===========================================================================
__global__ __launch_bounds__(256)
void agg_gather(const short* __restrict__ Hbf, const int* __restrict__ rowptr,
                const int* __restrict__ csr_src, const int* __restrict__ cnt1p,
                const int* __restrict__ cnt2p, const float* __restrict__ ee1l,
                const float* __restrict__ ee2l, short* __restrict__ outbf)
{
    int n    = blockIdx.x * 4 + (threadIdx.x >> 6);
    int lane = threadIdx.x & 63;
    if (n >= NN || lane >= 40) return;
    const uint4* HU = (const uint4*)Hbf;    // row stride = 40 uint4
    const int cb = lane * 8;                // first col of this lane

    int e   = rowptr[n];
    int end = rowptr[n + 1];

    // preload first index quad (in flight under the ee-table work below)
    int i0 = 0, i1 = 0, i2 = 0, i3 = 0;
    if (e + 4 <= end) {
        i0 = csr_src[e];     i1 = csr_src[e + 1];
        i2 = csr_src[e + 2]; i3 = csr_src[e + 3];
    }

    float aA[8], aB[8], aC[8], aD[8];
#pragma unroll
    for (int k = 0; k < 8; ++k) { aA[k] = 0.f; aB[k] = 0.f; aC[k] = 0.f; aD[k] = 0.f; }

    int p1 = cnt1p[n], p2 = cnt2p[n];
    float c10 = (float)(p1 & 1023), c11 = (float)((p1 >> 10) & 1023),
          c12 = (float)((p1 >> 20) & 1023);
    float c20 = (float)(p2 & 1023), c21 = (float)((p2 >> 10) & 1023),
          c22 = (float)((p2 >> 20) & 1023);

#define EEADD(rowp, s)                                                        \
    {                                                                         \
        if (lane <= 36) {                                                     \
            float4 v0 = *(const float4*)((rowp) + cb);                        \
            float4 v1 = *(const float4*)((rowp) + cb + 4);                    \
            aA[0] = fmaf(v0.x, (s), aA[0]); aA[1] = fmaf(v0.y, (s), aA[1]);   \
            aA[2] = fmaf(v0.z, (s), aA[2]); aA[3] = fmaf(v0.w, (s), aA[3]);   \
            aA[4] = fmaf(v1.x, (s), aA[4]); aA[5] = fmaf(v1.y, (s), aA[5]);   \
            aA[6] = fmaf(v1.z, (s), aA[6]); aA[7] = fmaf(v1.w, (s), aA[7]);   \
        } else if (lane == 37) {                                              \
            float4 v0 = *(const float4*)((rowp) + cb);                        \
            aA[0] = fmaf(v0.x, (s), aA[0]); aA[1] = fmaf(v0.y, (s), aA[1]);   \
            aA[2] = fmaf(v0.z, (s), aA[2]); aA[3] = fmaf(v0.w, (s), aA[3]);   \
        }                                                                     \
    }
    EEADD(ee1l + 4 * 300, 1.0f);      // self-loop bond type 4
    EEADD(ee1l, c10); EEADD(ee1l + 300, c11); EEADD(ee1l + 600, c12);
    EEADD(ee2l, c20 + 1.0f);          // self-loop dir 0 folded in
    EEADD(ee2l + 300, c21); EEADD(ee2l + 600, c22);
#undef EEADD

    // self row
    acc8(aB, HU[(size_t)n * 40 + lane]);

    while (e + 4 <= end) {
        uint4 v0 = HU[(size_t)i0 * 40 + lane];
        uint4 v1 = HU[(size_t)i1 * 40 + lane];
        uint4 v2 = HU[(size_t)i2 * 40 + lane];
        uint4 v3 = HU[(size_t)i3 * 40 + lane];
        e += 4;
        if (e + 4 <= end) {     // prefetch next index quad under consumption
            i0 = csr_src[e];     i1 = csr_src[e + 1];
            i2 = csr_src[e + 2]; i3 = csr_src[e + 3];
        }
        acc8(aA, v0); acc8(aB, v1); acc8(aC, v2); acc8(aD, v3);
    }
    for (; e < end; ++e) acc8(aA, HU[(size_t)csr_src[e] * 40 + lane]);

    uint4 o;
    o.x = pk2(aA[0] + aB[0] + aC[0] + aD[0], aA[1] + aB[1] + aC[1] + aD[1]);
    o.y = pk2(aA[2] + aB[2] + aC[2] + aD[2], aA[3] + aB[3] + aC[3] + aD[3]);
    o.z = pk2(aA[4] + aB[4] + aC[4] + aD[4], aA[5] + aB[5] + aC[5] + aD[5]);
    o.w = pk2(aA[6] + aB[6] + aC[6] + aD[6], aA[7] + aB[7] + aC[7] + aD[7]);
    ((uint4*)(outbf + (size_t)n * RS))[lane] = o;
}

// ===========================================================================
// MFMA fused MLP, barrier-free streaming, BM=64 + RING-3 DEPTH-2 PREFETCH:
//   X = relu(Y @ W1 + b1) @ W2 + b2
// 1024 thr = 16 waves: rt = w>>3 (32-row group), ch = w&7 (column group).
// R3's BM=64 geometry (2x weight reuse -> half the L2 traffic) combined with
// R4's ring-3 depth-2 prefetch (which fixed R3's depth-1 stall collapse).
// B fragments read DIRECTLY from packed global W1p/W2p (L2-resident) into a
// 3-slot register ring issued 2 k-steps ahead; A likewise. GEMM2: B ring-3
// from global, h ring-3 from LDS. ONE __syncthreads total.
// LDS = 77.8KB -> 2 blocks/CU = up to 8 waves/SIMD.
// ===========================================================================
__global__ __launch_bounds__(1024, 2)
void mlp_mfma(const short* __restrict__ Ybf, const short* __restrict__ W1p,
              const float* __restrict__ b1, const short* __restrict__ W2p,
              const float* __restrict__ b2, short* __restrict__ Xbf, int nrows)
{
    __shared__ __align__(16) short Hs[64 * 608];   // 77824 B
    char* HsB = (char*)Hs;
    const int tid  = threadIdx.x;
    const int w    = tid >> 6;
    const int ch   = w & 7;                // 0..7 column group
    const int rt   = w >> 3;               // 0..1 row group
    const int lane = tid & 63;
    const int row0 = blockIdx.x * 64;
    const int l15  = lane & 15;
    const int q    = lane >> 4;
    const int hr   = q * 4;
    const int rbase = rt * 32;

    const short* A0 = Ybf + (size_t)(row0 + rbase + l15) * RS;
    const short* A1 = A0 + 16 * RS;
    const char* W1B = (const char*)W1p + (ch * 5) * 1024 + lane * 16;
    const char* W2B = (const char*)W2p + (ch * 3) * 1024 + lane * 16;

    // ---- GEMM1: depth-2 prefetch rings (3 slots), no barriers ----
    f32x4 acc[5][2];
#pragma unroll
    for (int t = 0; t < 5; ++t) {
        acc[t][0] = (f32x4){0.f, 0.f, 0.f, 0.f};
        acc[t][1] = (f32x4){0.f, 0.f, 0.f, 0.f};
    }
    bf16x8 aa[3][2], bb[3][5];
#pragma unroll
    for (int p = 0; p < 2; ++p) {
        aa[p][0] = *(const bf16x8*)&A0[p * 32 + q * 8];
        aa[p][1] = *(const bf16x8*)&A1[p * 32 + q * 8];
        const char* src = W1B + p * (NT1 * 1024);
#pragma unroll
        for (int t = 0; t < 5; ++t) bb[p][t] = *(const bf16x8*)(src + t * 1024);
    }
#pragma unroll
    for (int kt = 0; kt < NK1; ++kt) {
        const int cur = kt % 3;
        if (kt + 2 < NK1) {
            const int nx = (kt + 2) % 3;
            aa[nx][0] = *(const bf16x8*)&A0[(kt + 2) * 32 + q * 8];
            aa[nx][1] = *(const bf16x8*)&A1[(kt + 2) * 32 + q * 8];
            const char* src = W1B + (kt + 2) * (NT1 * 1024);
#pragma unroll
            for (int t = 0; t < 5; ++t) bb[nx][t] = *(const bf16x8*)(src + t * 1024);
        }
#pragma unroll
        for (int t = 0; t < 5; ++t) {
            acc[t][0] = __builtin_amdgcn_mfma_f32_16x16x32_bf16(aa[cur][0], bb[cur][t], acc[t][0], 0, 0, 0);
            acc[t][1] = __builtin_amdgcn_mfma_f32_16x16x32_bf16(aa[cur][1], bb[cur][t], acc[t][1], 0, 0, 0);
        }
    }

    // ---- issue GEMM2 B[kt=0,1] loads early (in flight under epilogue) ----
    bf16x8 bfr[3][3];
#pragma unroll
    for (int p = 0; p < 2; ++p) {
        const char* src = W2B + p * (NT2 * 1024);
#pragma unroll
        for (int t = 0; t < 3; ++t) bfr[p][t] = *(const bf16x8*)(src + t * 1024);
    }

    // ---- epilogue 1: bias + relu -> Hs (cond-swizzled), one barrier ----
#pragma unroll
    for (int t = 0; t < 5; ++t) {
        int col = (ch * 5 + t) * 16 + l15;
        if (col < 608) {
            float bbv = col < 600 ? b1[col] : 0.0f;
#pragma unroll
            for (int m = 0; m < 2; ++m)
#pragma unroll
                for (int j = 0; j < 4; ++j) {
                    int row = rbase + m * 16 + hr + j;
                    float v = acc[t][m][j] + bbv;
                    v = v > 0.0f ? v : 0.0f;
                    int bo = 2 * col;
                    int boS = (bo < 1152) ? (bo ^ ((row & 7) << 4)) : bo;
                    *(short*)(HsB + row * HSTR + boS) = (short)f2bf(v);
                }
        }
    }
    __syncthreads();

    // ---- GEMM2: A from Hs (LDS, ring-3), B from global (ring-3) ----
    f32x4 acc2[3][2];
#pragma unroll
    for (int t = 0; t < 3; ++t) {
        acc2[t][0] = (f32x4){0.f, 0.f, 0.f, 0.f};
        acc2[t][1] = (f32x4){0.f, 0.f, 0.f, 0.f};
    }
    const int r0 = rbase + l15;
    const int r1 = r0 + 16;
    const int swz = (r0 & 7) << 4;       // r1&7 == r0&7
    bf16x8 hh[3][2];
#pragma unroll
    for (int p = 0; p < 2; ++p) {
        int bo  = p * 64 + q * 16;
        int boS = (bo < 1152) ? (bo ^ swz) : bo;
        hh[p][0] = *(const bf16x8*)(HsB + r0 * HSTR + boS);
        hh[p][1] = *(const bf16x8*)(HsB + r1 * HSTR + boS);
    }
#pragma unroll
    for (int kt = 0; kt < NK2; ++kt) {
        const int cur = kt % 3;
        if (kt + 2 < NK2) {
            const int nx = (kt + 2) % 3;
            const char* src = W2B + (kt + 2) * (NT2 * 1024);
#pragma unroll
            for (int t = 0; t < 3; ++t) bfr[nx][t] = *(const bf16x8*)(src + t * 1024);
            int bo  = (kt + 2) * 64 + q * 16;
            int boS = (bo < 1152) ? (bo ^ swz) : bo;
            hh[nx][0] = *(const bf16x8*)(HsB + r0 * HSTR + boS);
            hh[nx][1] = *(const bf16x8*)(HsB + r1 * HSTR + boS);
        }
#pragma unroll
        for (int t = 0; t < 3; ++t) {
            acc2[t][0] = __builtin_amdgcn_mfma_f32_16x16x32_bf16(hh[cur][0], bfr[cur][t], acc2[t][0], 0, 0, 0);
            acc2[t][1] = __builtin_amdgcn_mfma_f32_16x16x32_bf16(hh[cur][1], bfr[cur][t], acc2[t][1], 0, 0, 0);
        }
    }
#pragma unroll
    for (int t = 0; t < 3; ++t) {
        int col = (ch * 3 + t) * 16 + l15;
        if (col < 300) {
            float bbv = b2[col];
#pragma unroll
            for (int m = 0; m < 2; ++m)
#pragma unroll
                for (int j = 0; j < 4; ++j) {
                    int gr = row0 + rbase + m * 16 + hr + j;
                    if (gr < nrows)
                        Xbf[(size_t)gr * RS + col] = (short)f2bf(acc2[t][m][j] + bbv);
                }
        }
    }
}

// ===========================================================================
// global_add_pool over sorted batch (bf16 in stride 320, fp32 accum).
// 64 nodes/block, 160 threads (150 active), depth-1 clamped prefetch.
// ===========================================================================
__global__ __launch_bounds__(160)
void pool_kernel(const short* __restrict__ Xbf, const int* __restrict__ batch,
                 float* __restrict__ g)
{
    int tid = threadIdx.x;
    if (tid >= 150) return;
    int n0 = blockIdx.x * 64;
    int n1 = n0 + 64; if (n1 > NN) n1 = NN;
    int nlast = n1 - 1;
    float s0 = 0.0f, s1 = 0.0f;
    int cur = batch[n0];
    unsigned v = *(const unsigned*)&Xbf[(size_t)n0 * RS + tid * 2];
    for (int n = n0; n < n1; ++n) {
        int np = n + 1; np = np > nlast ? nlast : np;
        unsigned vnext = *(const unsigned*)&Xbf[(size_t)np * RS + tid * 2];
        int b = batch[n];
        if (b != cur) {
            atomicAdd(&g[cur * DD + tid * 2], s0);
            atomicAdd(&g[cur * DD + tid * 2 + 1], s1);
            s0 = 0.0f; s1 = 0.0f; cur = b;
        }
        s0 += __uint_as_float(v << 16);
        s1 += __uint_as_float(v & 0xffff0000u);
        v = vnext;
    }
    atomicAdd(&g[cur * DD + tid * 2], s0);
    atomicAdd(&g[cur * DD + tid * 2 + 1], s1);
}

// ===========================================================================
__global__ __launch_bounds__(160)
void head_kernel(const float* __restrict__ g, const float* __restrict__ l1W,
                 const float* __restrict__ l1b, const float* __restrict__ l2W,
                 const float* __restrict__ l2b, float* __restrict__ out)
{
    __shared__ float g2s[152];
    int r = blockIdx.x, tid = threadIdx.x;
    const float* gr = g + r * DD;
    if (tid < 150) {
        float acc = 0.0f;
        for (int k = 0; k < DD; ++k) acc = fmaf(gr[k], l1W[k * 150 + tid], acc);
        acc += l1b[tid];
        g2s[tid] = acc > 0.0f ? acc : 0.0f;
    }
    __syncthreads();
    if (tid < 128) {
        float acc = 0.0f;
        for (int k = 0; k < 150; ++k) acc = fmaf(g2s[k], l2W[k * 128 + tid], acc);
        out[r * 128 + tid] = acc + l2b[tid];
    }
}

// ===========================================================================
extern "C" void kernel_launch(void* const* d_in, const int* in_sizes, int n_in,
                              void* d_out, int out_size, void* d_ws, size_t ws_size,
                              hipStream_t stream)
{
    const float* x     = (const float*)d_in[0];
    const float* W1    = (const float*)d_in[1];
    const float* b1    = (const float*)d_in[2];
    const float* W2    = (const float*)d_in[3];
    const float* b2    = (const float*)d_in[4];
    const float* ee1   = (const float*)d_in[5];
    const float* ee2   = (const float*)d_in[6];
    const float* l1W   = (const float*)d_in[7];
    const float* l1b   = (const float*)d_in[8];
    const float* l2W   = (const float*)d_in[9];
    const float* l2b   = (const float*)d_in[10];
    const int*   ei    = (const int*)d_in[11];
    const int*   ea    = (const int*)d_in[12];
    const int*   batch = (const int*)d_in[13];
    float* out = (float*)d_out;

    short* Xbf = (short*)d_ws;                       // NN x 320 bf16
    short* Ybf = Xbf + (size_t)NN * RS;              // (NN+64) x 320 bf16
    float* g   = (float*)(Ybf + (size_t)(NN + 64) * RS);
    short* W1p = (short*)(g + (size_t)GG * DD);
    short* W2p = W1p + 5 * PACK1;
    int* rowptr  = (int*)(W2p + 5 * PACK2);          // N+1
    int* cursor  = rowptr + NN + 1;
    int* csr_src = cursor + NN;
    int* cnt1p   = csr_src + EE;                     // cnt1p,cnt2p contiguous
    int* cnt2p   = cnt1p + NN;
    int* blocksum = cnt2p + NN;                      // SCB ints

    hipMemsetAsync(g, 0, (size_t)GG * DD * sizeof(float), stream);
    hipMemsetAsync(cnt1p, 0, (size_t)2 * NN * sizeof(int), stream);

    count_kernel<<<(EE + 255) / 256, 256, 0, stream>>>(ei, ea, cnt1p, cnt2p);
    scan1_kernel<<<SCB, 256, 0, stream>>>(cnt1p, blocksum);
    scan2_kernel<<<SCB, 256, 0, stream>>>(cnt1p, blocksum, rowptr, cursor);
    fill_kernel<<<(EE + 255) / 256, 256, 0, stream>>>(ei, cursor, csr_src);

    {
        const int TL = NT1 * NK1 + NT2 * NK2;
        pack_all<<<(5 * TL * 64 + 255) / 256, 256, 0, stream>>>(W1, W2, W1p, W2p);
    }
    {
        int total = NN * RSU + (NN + 64) * 5;
        init_kernel<<<(total + 255) / 256, 256, 0, stream>>>(x, Xbf, Ybf);
    }

    for (int l = 0; l < 5; ++l) {
        const float* ee1l = ee1 + (size_t)l * 6 * DD;
        const float* ee2l = ee2 + (size_t)l * 3 * DD;
        agg_gather<<<(NN + 3) / 4, 256, 0, stream>>>(
            Xbf, rowptr, csr_src, cnt1p, cnt2p, ee1l, ee2l, Ybf);
        mlp_mfma<<<(NN + 63) / 64, 1024, 0, stream>>>(
            Ybf, W1p + l * PACK1, b1 + (size_t)l * 600,
            W2p + l * PACK2, b2 + (size_t)l * DD, Xbf, NN);
    }
    pool_kernel<<<(NN + 63) / 64, 160, 0, stream>>>(Xbf, batch, g);
    head_kernel<<<GG, 160, 0, stream>>>(g, l1W, l1b, l2W, l2b, out);
}

// Round 12
// 1111.601 us; speedup vs baseline: 1.0639x; 1.0639x over previous
//
#include <hip/hip_runtime.h>
#include <hip/hip_bf16.h>

#define NN 50000
#define EE 800000
#define DD 300
#define GG 256
#define RS  320            // padded activation row stride (shorts)
#define RSU 80             // row stride in uint2

// GEMM geometry
#define NK1 10             // GEMM1 k-steps (K=320)
#define NT1 40             // GEMM1 col tiles (N=640)
#define NK2 19             // GEMM2 k-steps (K=608)
#define NT2 24             // GEMM2 col tiles (N=384)
#define PACK1 ((size_t)NT1 * NK1 * 512)   // shorts per layer
#define PACK2 ((size_t)NT2 * NK2 * 512)
#define HSTR 1216          // Hs row stride bytes (608 bf16)

#define SCB 49             // scan blocks (49 * 1024 >= NN)

typedef short bf16x8 __attribute__((ext_vector_type(8)));
typedef float f32x4  __attribute__((ext_vector_type(4)));

// float -> bf16 bits, round-to-nearest-even (finite inputs)
__device__ inline unsigned short f2bf(float f) {
    unsigned u = __float_as_uint(f);
    return (unsigned short)((u + 0x7fffu + ((u >> 16) & 1u)) >> 16);
}
__device__ inline unsigned pk2(float a, float b) {
    return (unsigned)f2bf(a) | ((unsigned)f2bf(b) << 16);
}
// a[0..7] += 8 bf16 unpacked from uint4
__device__ inline void acc8(float* a, uint4 v) {
    a[0] += __uint_as_float(v.x << 16); a[1] += __uint_as_float(v.x & 0xffff0000u);
    a[2] += __uint_as_float(v.y << 16); a[3] += __uint_as_float(v.y & 0xffff0000u);
    a[4] += __uint_as_float(v.z << 16); a[5] += __uint_as_float(v.z & 0xffff0000u);
    a[6] += __uint_as_float(v.w << 16); a[7] += __uint_as_float(v.w & 0xffff0000u);
}
__device__ inline int deg3(int p) {
    return (p & 1023) + ((p >> 10) & 1023) + ((p >> 20) & 1023);
}

// ===========================================================================
// CSR build (once per launch). deg derived from cnt1p (3x10-bit counts).
// ===========================================================================
__global__ __launch_bounds__(256)
void count_kernel(const int* __restrict__ ei, const int* __restrict__ ea,
                  int* __restrict__ cnt1p, int* __restrict__ cnt2p)
{
    int e = blockIdx.x * 256 + threadIdx.x;
    if (e >= EE) return;
    int dst = ei[EE + e];
    int a0  = ea[e * 2];
    int a1  = ea[e * 2 + 1];
    atomicAdd(&cnt1p[dst], 1 << (10 * a0));
    atomicAdd(&cnt2p[dst], 1 << (10 * a1));
}

// Hierarchical scan, phase 1: per-block degree sums (49 blocks x 1024 nodes)
__global__ __launch_bounds__(256)
void scan1_kernel(const int* __restrict__ cnt1p, int* __restrict__ blocksum)
{
    __shared__ int ws[4];
    int tid = threadIdx.x;
    int n0 = blockIdx.x * 1024 + tid * 4;
    int s = 0;
#pragma unroll
    for (int i = 0; i < 4; ++i) {
        int n = n0 + i;
        if (n < NN) s += deg3(cnt1p[n]);
    }
    for (int off = 1; off < 64; off <<= 1) s += __shfl_xor(s, off);
    if ((tid & 63) == 0) ws[tid >> 6] = s;
    __syncthreads();
    if (tid == 0) blocksum[blockIdx.x] = ws[0] + ws[1] + ws[2] + ws[3];
}

// Hierarchical scan, phase 2: block offset via predicated 64-lane reduce over
// the 49 block sums, intra-block shfl_up scan, write rowptr+cursor.
__global__ __launch_bounds__(256)
void scan2_kernel(const int* __restrict__ cnt1p, const int* __restrict__ blocksum,
                  int* __restrict__ rowptr, int* __restrict__ cursor)
{
    __shared__ int ws[4];
    __shared__ int boff;
    int tid = threadIdx.x;
    int b   = blockIdx.x;
    if (tid < 64) {
        int v = (tid < b) ? blocksum[tid] : 0;     // b <= 48 < 64
        for (int off = 1; off < 64; off <<= 1) v += __shfl_xor(v, off);
        if (tid == 0) boff = v;
    }
    int n0 = b * 1024 + tid * 4;
    int d[4]; int s = 0;
#pragma unroll
    for (int i = 0; i < 4; ++i) {
        int n = n0 + i;
        d[i] = (n < NN) ? deg3(cnt1p[n]) : 0;
        s += d[i];
    }
    int lane = tid & 63, w = tid >> 6;
    int inc = s;
    for (int off = 1; off < 64; off <<= 1) {
        int t = __shfl_up(inc, off);
        if (lane >= off) inc += t;
    }
    if (lane == 63) ws[w] = inc;
    __syncthreads();
    int woff = 0;
#pragma unroll
    for (int i = 0; i < 4; ++i) if (i < w) woff += ws[i];
    int excl = boff + woff + inc - s;
#pragma unroll
    for (int i = 0; i < 4; ++i) {
        int n = n0 + i;
        if (n < NN) { rowptr[n] = excl; cursor[n] = excl; }
        excl += d[i];
    }
    if (b == SCB - 1 && tid == 255) rowptr[NN] = EE;
}

__global__ __launch_bounds__(256)
void fill_kernel(const int* __restrict__ ei, int* __restrict__ cursor,
                 int* __restrict__ csr_src)
{
    int e = blockIdx.x * 256 + threadIdx.x;
    if (e >= EE) return;
    int dst = ei[EE + e];
    int src = ei[e];
    int pos = atomicAdd(&cursor[dst], 1);
    csr_src[pos] = src;
}

// ===========================================================================
// Pack ALL layers' W1+W2 -> bf16 MFMA B-fragments, kt-major:
// tile (nt_i,kt) at pos = kt*NT + nt_i. Lane l holds
// B[kt*32 + (l>>4)*8 + j][nt_i*16 + (l&15)], zero-padded outside K x N.
// ===========================================================================
__global__ __launch_bounds__(256)
void pack_all(const float* __restrict__ W1, const float* __restrict__ W2,
              short* __restrict__ W1p, short* __restrict__ W2p)
{
    const int TL = NT1 * NK1 + NT2 * NK2;   // 856 tiles/layer
    int idx = blockIdx.x * 256 + threadIdx.x;
    if (idx >= 5 * TL * 64) return;
    int lane  = idx & 63;
    int tile  = idx >> 6;
    int layer = tile / TL;
    int tl    = tile - layer * TL;
    const float* W; short* outp;
    int K, N, nt_i, kt, pos;
    if (tl < NT1 * NK1) {
        nt_i = tl / NK1; kt = tl % NK1;
        W = W1 + (size_t)layer * DD * 600;
        outp = W1p + layer * PACK1;
        K = 300; N = 600;
        pos = kt * NT1 + nt_i;
    } else {
        tl -= NT1 * NK1;
        nt_i = tl / NK2; kt = tl % NK2;
        W = W2 + (size_t)layer * 600 * DD;
        outp = W2p + layer * PACK2;
        K = 600; N = 300;
        pos = kt * NT2 + nt_i;
    }
    int col = nt_i * 16 + (lane & 15);
    int k0  = kt * 32 + (lane >> 4) * 8;
    unsigned short v[8];
#pragma unroll
    for (int j = 0; j < 8; ++j) {
        int r = k0 + j;
        float f = (r < K && col < N) ? W[(size_t)r * N + col] : 0.0f;
        v[j] = f2bf(f);
    }
    uint4 p;
    p.x = (unsigned)v[0] | ((unsigned)v[1] << 16);
    p.y = (unsigned)v[2] | ((unsigned)v[3] << 16);
    p.z = (unsigned)v[4] | ((unsigned)v[5] << 16);
    p.w = (unsigned)v[6] | ((unsigned)v[7] << 16);
    ((uint4*)outp)[(size_t)pos * 64 + lane] = p;
}

// ===========================================================================
// init: x (fp32 [N][300]) -> Xbf bf16 [N][320] zero-padded; zero Ybf pad cols.
// ===========================================================================
__global__ __launch_bounds__(256)
void init_kernel(const float* __restrict__ x, short* __restrict__ Xbf,
                 short* __restrict__ Ybf)
{
    int i = blockIdx.x * 256 + threadIdx.x;
    const int TX = NN * RSU;
    if (i < TX) {
        int row = i / RSU, pu = i - row * RSU;
        uint2 o = make_uint2(0u, 0u);
        if (pu < 75) {
            float4 v = ((const float4*)x)[row * 75 + pu];
            o = make_uint2(pk2(v.x, v.y), pk2(v.z, v.w));
        }
        ((uint2*)Xbf)[i] = o;
    } else {
        int j = i - TX;
        if (j < (NN + 64) * 5) {
            int row = j / 5, pu = 75 + (j - row * 5);
            ((uint2*)Ybf)[(size_t)row * RSU + pu] = make_uint2(0u, 0u);
        }
    }
}

// ===========================================================================
// Aggregation: one wave per node, 40 active lanes, uint4 (16B) row chunks,
// depth-4 pipeline + INDEX PREFETCH (R10-proven, ~100us): next iteration's 4
// csr_src indices loaded while current rows are consumed.
// agg[n] = h[n] + ee-self + sum_t cnt*ee[t] + sum_in h[src]
// ===========================================================================
__global__ __launch_bounds__(256)
void agg_gather(const short* __restrict__ Hbf, const int* __restrict__ rowptr,
                const int* __restrict__ csr_src, const int* __restrict__ cnt1p,
                const int* __restrict__ cnt2p, const float* __restrict__ ee1l,
                const float* __restrict__ ee2l, short* __restrict__ outbf)
{
    int n    = blockIdx.x * 4 + (threadIdx.x >> 6);
    int lane = threadIdx.x & 63;
    if (n >= NN || lane >= 40) return;
    const uint4* HU = (const uint4*)Hbf;    // row stride = 40 uint4
    const int cb = lane * 8;                // first col of this lane

    int e   = rowptr[n];
    int end = rowptr[n + 1];

    // preload first index quad (in flight under the ee-table work below)
    int i0 = 0, i1 = 0, i2 = 0, i3 = 0;
    if (e + 4 <= end) {
        i0 = csr_src[e];     i1 = csr_src[e + 1];
        i2 = csr_src[e + 2]; i3 = csr_src[e + 3];
    }

    float aA[8], aB[8], aC[8], aD[8];
#pragma unroll
    for (int k = 0; k < 8; ++k) { aA[k] = 0.f; aB[k] = 0.f; aC[k] = 0.f; aD[k] = 0.f; }

    int p1 = cnt1p[n], p2 = cnt2p[n];
    float c10 = (float)(p1 & 1023), c11 = (float)((p1 >> 10) & 1023),
          c12 = (float)((p1 >> 20) & 1023);
    float c20 = (float)(p2 & 1023), c21 = (float)((p2 >> 10) & 1023),
          c22 = (float)((p2 >> 20) & 1023);

#define EEADD(rowp, s)                                                        \
    {                                                                         \
        if (lane <= 36) {                                                     \
            float4 v0 = *(const float4*)((rowp) + cb);                        \
            float4 v1 = *(const float4*)((rowp) + cb + 4);                    \
            aA[0] = fmaf(v0.x, (s), aA[0]); aA[1] = fmaf(v0.y, (s), aA[1]);   \
            aA[2] = fmaf(v0.z, (s), aA[2]); aA[3] = fmaf(v0.w, (s), aA[3]);   \
            aA[4] = fmaf(v1.x, (s), aA[4]); aA[5] = fmaf(v1.y, (s), aA[5]);   \
            aA[6] = fmaf(v1.z, (s), aA[6]); aA[7] = fmaf(v1.w, (s), aA[7]);   \
        } else if (lane == 37) {                                              \
            float4 v0 = *(const float4*)((rowp) + cb);                        \
            aA[0] = fmaf(v0.x, (s), aA[0]); aA[1] = fmaf(v0.y, (s), aA[1]);   \
            aA[2] = fmaf(v0.z, (s), aA[2]); aA[3] = fmaf(v0.w, (s), aA[3]);   \
        }                                                                     \
    }
    EEADD(ee1l + 4 * 300, 1.0f);      // self-loop bond type 4
    EEADD(ee1l, c10); EEADD(ee1l + 300, c11); EEADD(ee1l + 600, c12);
    EEADD(ee2l, c20 + 1.0f);          // self-loop dir 0 folded in
    EEADD(ee2l + 300, c21); EEADD(ee2l + 600, c22);
#undef EEADD

    // self row
    acc8(aB, HU[(size_t)n * 40 + lane]);

    while (e + 4 <= end) {
        uint4 v0 = HU[(size_t)i0 * 40 + lane];
        uint4 v1 = HU[(size_t)i1 * 40 + lane];
        uint4 v2 = HU[(size_t)i2 * 40 + lane];
        uint4 v3 = HU[(size_t)i3 * 40 + lane];
        e += 4;
        if (e + 4 <= end) {     // prefetch next index quad under consumption
            i0 = csr_src[e];     i1 = csr_src[e + 1];
            i2 = csr_src[e + 2]; i3 = csr_src[e + 3];
        }
        acc8(aA, v0); acc8(aB, v1); acc8(aC, v2); acc8(aD, v3);
    }
    for (; e < end; ++e) acc8(aA, HU[(size_t)csr_src[e] * 40 + lane]);

    uint4 o;
    o.x = pk2(aA[0] + aB[0] + aC[0] + aD[0], aA[1] + aB[1] + aC[1] + aD[1]);
    o.y = pk2(aA[2] + aB[2] + aC[2] + aD[2], aA[3] + aB[3] + aC[3] + aD[3]);
    o.z = pk2(aA[4] + aB[4] + aC[4] + aD[4], aA[5] + aB[5] + aC[5] + aD[5]);
    o.w = pk2(aA[6] + aB[6] + aC[6] + aD[6], aA[7] + aB[7] + aC[7] + aD[7]);
    ((uint4*)(outbf + (size_t)n * RS))[lane] = o;
}

// ===========================================================================
// MFMA fused MLP, barrier-free streaming, BM=32, RING-3 DEPTH-2 PREFETCH
// (R10-proven structure) + K-LOOP ROTATION: block b starts its k-sweep at
// kt = b mod NK (wrapping), so co-resident blocks read DIFFERENT weight
// lines at any instant — breaks the L2 same-line broadcast hotspot where
// all 32 CUs of an XCD hit one L2 slice simultaneously.
//   X = relu(Y @ W1 + b1) @ W2 + b2
// ===========================================================================
__global__ __launch_bounds__(512, 3)
void mlp_mfma(const short* __restrict__ Ybf, const short* __restrict__ W1p,
              const float* __restrict__ b1, const short* __restrict__ W2p,
              const float* __restrict__ b2, short* __restrict__ Xbf, int nrows)
{
    __shared__ __align__(16) short Hs[32 * 608];   // 38912 B
    char* HsB = (char*)Hs;
    const int tid  = threadIdx.x;
    const int ch   = tid >> 6;             // 0..7 column group
    const int lane = tid & 63;
    const int row0 = blockIdx.x * 32;
    const int l15  = lane & 15;
    const int q    = lane >> 4;
    const int hr   = q * 4;
    const int rot1 = blockIdx.x % NK1;     // k-rotation offsets
    const int rot2 = blockIdx.x % NK2;

    const short* A0 = Ybf + (size_t)(row0 + l15) * RS;
    const short* A1 = A0 + 16 * RS;
    const char* W1B = (const char*)W1p + (ch * 5) * 1024 + lane * 16;
    const char* W2B = (const char*)W2p + (ch * 3) * 1024 + lane * 16;

    // ---- GEMM1: depth-2 prefetch rings (3 slots), rotated k-order ----
    f32x4 acc[5][2];
#pragma unroll
    for (int t = 0; t < 5; ++t) {
        acc[t][0] = (f32x4){0.f, 0.f, 0.f, 0.f};
        acc[t][1] = (f32x4){0.f, 0.f, 0.f, 0.f};
    }
    bf16x8 aa[3][2], bb[3][5];
#pragma unroll
    for (int p = 0; p < 2; ++p) {
        int kidx = rot1 + p; if (kidx >= NK1) kidx -= NK1;
        aa[p][0] = *(const bf16x8*)&A0[kidx * 32 + q * 8];
        aa[p][1] = *(const bf16x8*)&A1[kidx * 32 + q * 8];
        const char* src = W1B + kidx * (NT1 * 1024);
#pragma unroll
        for (int t = 0; t < 5; ++t) bb[p][t] = *(const bf16x8*)(src + t * 1024);
    }
#pragma unroll
    for (int kt = 0; kt < NK1; ++kt) {
        const int cur = kt % 3;
        if (kt + 2 < NK1) {
            const int nx = (kt + 2) % 3;
            int kidx = rot1 + kt + 2; if (kidx >= NK1) kidx -= NK1;
            aa[nx][0] = *(const bf16x8*)&A0[kidx * 32 + q * 8];
            aa[nx][1] = *(const bf16x8*)&A1[kidx * 32 + q * 8];
            const char* src = W1B + kidx * (NT1 * 1024);
#pragma unroll
            for (int t = 0; t < 5; ++t) bb[nx][t] = *(const bf16x8*)(src + t * 1024);
        }
#pragma unroll
        for (int t = 0; t < 5; ++t) {
            acc[t][0] = __builtin_amdgcn_mfma_f32_16x16x32_bf16(aa[cur][0], bb[cur][t], acc[t][0], 0, 0, 0);
            acc[t][1] = __builtin_amdgcn_mfma_f32_16x16x32_bf16(aa[cur][1], bb[cur][t], acc[t][1], 0, 0, 0);
        }
    }

    // ---- issue GEMM2 B loads early (rotated; in flight under epilogue) ----
    bf16x8 bfr[3][3];
#pragma unroll
    for (int p = 0; p < 2; ++p) {
        int kidx = rot2 + p; if (kidx >= NK2) kidx -= NK2;
        const char* src = W2B + kidx * (NT2 * 1024);
#pragma unroll
        for (int t = 0; t < 3; ++t) bfr[p][t] = *(const bf16x8*)(src + t * 1024);
    }

    // ---- epilogue 1: bias + relu -> Hs (cond-swizzled), one barrier ----
#pragma unroll
    for (int t = 0; t < 5; ++t) {
        int col = (ch * 5 + t) * 16 + l15;
        if (col < 608) {
            float bbv = col < 600 ? b1[col] : 0.0f;
#pragma unroll
            for (int m = 0; m < 2; ++m)
#pragma unroll
                for (int j = 0; j < 4; ++j) {
                    int row = m * 16 + hr + j;
                    float v = acc[t][m][j] + bbv;
                    v = v > 0.0f ? v : 0.0f;
                    int bo = 2 * col;
                    int boS = (bo < 1152) ? (bo ^ ((row & 7) << 4)) : bo;
                    *(short*)(HsB + row * HSTR + boS) = (short)f2bf(v);
                }
        }
    }
    __syncthreads();

    // ---- GEMM2: A from Hs (LDS, ring-3), B from global (ring-3), rotated ----
    f32x4 acc2[3][2];
#pragma unroll
    for (int t = 0; t < 3; ++t) {
        acc2[t][0] = (f32x4){0.f, 0.f, 0.f, 0.f};
        acc2[t][1] = (f32x4){0.f, 0.f, 0.f, 0.f};
    }
    const int r0 = l15;
    const int r1 = r0 + 16;
    const int swz = (r0 & 7) << 4;       // r1&7 == r0&7
    bf16x8 hh[3][2];
#pragma unroll
    for (int p = 0; p < 2; ++p) {
        int kidx = rot2 + p; if (kidx >= NK2) kidx -= NK2;
        int bo  = kidx * 64 + q * 16;
        int boS = (bo < 1152) ? (bo ^ swz) : bo;
        hh[p][0] = *(const bf16x8*)(HsB + r0 * HSTR + boS);
        hh[p][1] = *(const bf16x8*)(HsB + r1 * HSTR + boS);
    }
#pragma unroll
    for (int kt = 0; kt < NK2; ++kt) {
        const int cur = kt % 3;
        if (kt + 2 < NK2) {
            const int nx = (kt + 2) % 3;
            int kidx = rot2 + kt + 2;
            if (kidx >= NK2) kidx -= NK2;
            if (kidx >= NK2) kidx -= NK2;
            const char* src = W2B + kidx * (NT2 * 1024);
#pragma unroll
            for (int t = 0; t < 3; ++t) bfr[nx][t] = *(const bf16x8*)(src + t * 1024);
            int bo  = kidx * 64 + q * 16;
            int boS = (bo < 1152) ? (bo ^ swz) : bo;
            hh[nx][0] = *(const bf16x8*)(HsB + r0 * HSTR + boS);
            hh[nx][1] = *(const bf16x8*)(HsB + r1 * HSTR + boS);
        }
#pragma unroll
        for (int t = 0; t < 3; ++t) {
            acc2[t][0] = __builtin_amdgcn_mfma_f32_16x16x32_bf16(hh[cur][0], bfr[cur][t], acc2[t][0], 0, 0, 0);
            acc2[t][1] = __builtin_amdgcn_mfma_f32_16x16x32_bf16(hh[cur][1], bfr[cur][t], acc2[t][1], 0, 0, 0);
        }
    }
#pragma unroll
    for (int t = 0; t < 3; ++t) {
        int col = (ch * 3 + t) * 16 + l15;
        if (col < 300) {
            float bbv = b2[col];
#pragma unroll
            for (int m = 0; m < 2; ++m)
#pragma unroll
                for (int j = 0; j < 4; ++j) {
                    int gr = row0 + m * 16 + hr + j;
                    if (gr < nrows)
                        Xbf[(size_t)gr * RS + col] = (short)f2bf(acc2[t][m][j] + bbv);
                }
        }
    }
}

// ===========================================================================
// global_add_pool over sorted batch (bf16 in stride 320, fp32 accum).
// 64 nodes/block, 160 threads (150 active), depth-1 clamped prefetch.
// ===========================================================================
__global__ __launch_bounds__(160)
void pool_kernel(const short* __restrict__ Xbf, const int* __restrict__ batch,
                 float* __restrict__ g)
{
    int tid = threadIdx.x;
    if (tid >= 150) return;
    int n0 = blockIdx.x * 64;
    int n1 = n0 + 64; if (n1 > NN) n1 = NN;
    int nlast = n1 - 1;
    float s0 = 0.0f, s1 = 0.0f;
    int cur = batch[n0];
    unsigned v = *(const unsigned*)&Xbf[(size_t)n0 * RS + tid * 2];
    for (int n = n0; n < n1; ++n) {
        int np = n + 1; np = np > nlast ? nlast : np;
        unsigned vnext = *(const unsigned*)&Xbf[(size_t)np * RS + tid * 2];
        int b = batch[n];
        if (b != cur) {
            atomicAdd(&g[cur * DD + tid * 2], s0);
            atomicAdd(&g[cur * DD + tid * 2 + 1], s1);
            s0 = 0.0f; s1 = 0.0f; cur = b;
        }
        s0 += __uint_as_float(v << 16);
        s1 += __uint_as_float(v & 0xffff0000u);
        v = vnext;
    }
    atomicAdd(&g[cur * DD + tid * 2], s0);
    atomicAdd(&g[cur * DD + tid * 2 + 1], s1);
}

// ===========================================================================
__global__ __launch_bounds__(160)
void head_kernel(const float* __restrict__ g, const float* __restrict__ l1W,
                 const float* __restrict__ l1b, const float* __restrict__ l2W,
                 const float* __restrict__ l2b, float* __restrict__ out)
{
    __shared__ float g2s[152];
    int r = blockIdx.x, tid = threadIdx.x;
    const float* gr = g + r * DD;
    if (tid < 150) {
        float acc = 0.0f;
        for (int k = 0; k < DD; ++k) acc = fmaf(gr[k], l1W[k * 150 + tid], acc);
        acc += l1b[tid];
        g2s[tid] = acc > 0.0f ? acc : 0.0f;
    }
    __syncthreads();
    if (tid < 128) {
        float acc = 0.0f;
        for (int k = 0; k < 150; ++k) acc = fmaf(g2s[k], l2W[k * 128 + tid], acc);
        out[r * 128 + tid] = acc + l2b[tid];
    }
}

// ===========================================================================
extern "C" void kernel_launch(void* const* d_in, const int* in_sizes, int n_in,
                              void* d_out, int out_size, void* d_ws, size_t ws_size,
                              hipStream_t stream)
{
    const float* x     = (const float*)d_in[0];
    const float* W1    = (const float*)d_in[1];
    const float* b1    = (const float*)d_in[2];
    const float* W2    = (const float*)d_in[3];
    const float* b2    = (const float*)d_in[4];
    const float* ee1   = (const float*)d_in[5];
    const float* ee2   = (const float*)d_in[6];
    const float* l1W   = (const float*)d_in[7];
    const float* l1b   = (const float*)d_in[8];
    const float* l2W   = (const float*)d_in[9];
    const float* l2b   = (const float*)d_in[10];
    const int*   ei    = (const int*)d_in[11];
    const int*   ea    = (const int*)d_in[12];
    const int*   batch = (const int*)d_in[13];
    float* out = (float*)d_out;

    short* Xbf = (short*)d_ws;                       // NN x 320 bf16
    short* Ybf = Xbf + (size_t)NN * RS;              // (NN+64) x 320 bf16
    float* g   = (float*)(Ybf + (size_t)(NN + 64) * RS);
    short* W1p = (short*)(g + (size_t)GG * DD);
    short* W2p = W1p + 5 * PACK1;
    int* rowptr  = (int*)(W2p + 5 * PACK2);          // N+1
    int* cursor  = rowptr + NN + 1;
    int* csr_src = cursor + NN;
    int* cnt1p   = csr_src + EE;                     // cnt1p,cnt2p contiguous
    int* cnt2p   = cnt1p + NN;
    int* blocksum = cnt2p + NN;                      // SCB ints

    hipMemsetAsync(g, 0, (size_t)GG * DD * sizeof(float), stream);
    hipMemsetAsync(cnt1p, 0, (size_t)2 * NN * sizeof(int), stream);

    count_kernel<<<(EE + 255) / 256, 256, 0, stream>>>(ei, ea, cnt1p, cnt2p);
    scan1_kernel<<<SCB, 256, 0, stream>>>(cnt1p, blocksum);
    scan2_kernel<<<SCB, 256, 0, stream>>>(cnt1p, blocksum, rowptr, cursor);
    fill_kernel<<<(EE + 255) / 256, 256, 0, stream>>>(ei, cursor, csr_src);

    {
        const int TL = NT1 * NK1 + NT2 * NK2;
        pack_all<<<(5 * TL * 64 + 255) / 256, 256, 0, stream>>>(W1, W2, W1p, W2p);
    }
    {
        int total = NN * RSU + (NN + 64) * 5;
        init_kernel<<<(total + 255) / 256, 256, 0, stream>>>(x, Xbf, Ybf);
    }

    for (int l = 0; l < 5; ++l) {
        const float* ee1l = ee1 + (size_t)l * 6 * DD;
        const float* ee2l = ee2 + (size_t)l * 3 * DD;
        agg_gather<<<(NN + 3) / 4, 256, 0, stream>>>(
            Xbf, rowptr, csr_src, cnt1p, cnt2p, ee1l, ee2l, Ybf);
        mlp_mfma<<<(NN + 31) / 32, 512, 0, stream>>>(
            Ybf, W1p + l * PACK1, b1 + (size_t)l * 600,
            W2p + l * PACK2, b2 + (size_t)l * DD, Xbf, NN);
    }
    pool_kernel<<<(NN + 63) / 64, 160, 0, stream>>>(Xbf, batch, g);
    head_kernel<<<GG, 160, 0, stream>>>(g, l1W, l1b, l2W, l2b, out);
}